// Round 2
// baseline (320.689 us; speedup 1.0000x reference)
//
#include <hip/hip_runtime.h>

// GlobalQuantizedLatent: per-element nearest-codebook quantization.
// N = 16,777,216 f32, V = 16 codebook entries (linspace(-0.5, 0.5, 16)).
// Outputs (concatenated flat, all f32):
//   [0,   N) : x            (copy of input)
//   [N,  2N) : quantized    (values[argmin |x - values|])
//   [2N, 3N) : z_hat        (== quantized numerically in forward)
//   [3N, 4N) : indices      (argmin index, stored as float)
//
// Memory-bound: 64 MiB read + 256 MiB write => ~53 us floor at 6.3 TB/s.
//
// KEY FIX this round: the previous kernel did `q[e] = v[bi]` with a RUNTIME
// index bi into the v[16] codebook array. One dynamic index defeats SROA ->
// v[] lives in scratch (private mem through L2): 16 scratch stores + 8
// dynamic scratch loads per thread, ~190 MB of extra traffic + ~200 cyc
// dependent latency per element. That matches the observed ~2.4 TB/s
// effective kernel BW while the adjacent poison-fill hits 6.4 TB/s.
// Now the compare chain CARRIES the best value and best index as registers
// (compile-time j only) -> pure v_cndmask chain, zero scratch.
//
// Also: plain (cached) load for x — 64 MiB, re-read each bench iteration,
// fits the 256 MiB LLC; NT hint kept on stores only (write-once data).

#define BLOCK 256
#define NVALS 16

typedef float f32x4 __attribute__((ext_vector_type(4)));

__device__ __forceinline__ void argmin16(const float xs, const float* __restrict__ v,
                                         float& q, float& idxf) {
    // Exact replication of jnp.argmin(|x - values|): first minimum wins
    // (strict <), scanning j ascending — bit-for-bit the reference tie-break.
    float best = fabsf(xs - v[0]);
    float bq   = v[0];
    float bif  = 0.0f;
#pragma unroll
    for (int j = 1; j < NVALS; ++j) {
        const float d  = fabsf(xs - v[j]);
        const bool  lt = d < best;
        best = lt ? d : best;          // all selects on compile-time j:
        bq   = lt ? v[j] : bq;         // -> v_cndmask chain, no scratch
        bif  = lt ? (float)j : bif;
    }
    q = bq;
    idxf = bif;
}

__global__ __launch_bounds__(BLOCK) void
GlobalQuantizedLatent_87900800680047_kernel(const float* __restrict__ x,
                                            const float* __restrict__ values,
                                            float* __restrict__ out,
                                            int n) {
    const int tid     = blockIdx.x * BLOCK + threadIdx.x;
    const int stride  = gridDim.x * BLOCK;      // 2,097,152 threads
    const int nchunks = n >> 2;                 // 4,194,304 float4 chunks

    // Codebook: wave-uniform pointer + constant offsets -> scalar loads;
    // only constant indices below, so v[] is fully register-promoted.
    float v[NVALS];
#pragma unroll
    for (int j = 0; j < NVALS; ++j) v[j] = values[j];

    const size_t nn = (size_t)n;
    float* __restrict__ o_q   = out + nn;
    float* __restrict__ o_zh  = out + 2 * nn;
    float* __restrict__ o_idx = out + 3 * nn;

    // Exactly 2 chunks per thread at N = 2^24; both loads issued up front.
    const int c0 = tid;
    const int c1 = tid + stride;

    f32x4 xa, xb;
    if (c0 < nchunks) xa = *reinterpret_cast<const f32x4*>(x + (c0 << 2));
    if (c1 < nchunks) xb = *reinterpret_cast<const f32x4*>(x + (c1 << 2));

    if (c0 < nchunks) {
        const int i4 = c0 << 2;
        f32x4 qv, iv;
#pragma unroll
        for (int e = 0; e < 4; ++e) { float q, f; argmin16(xa[e], v, q, f); qv[e] = q; iv[e] = f; }
        __builtin_nontemporal_store(xa, reinterpret_cast<f32x4*>(out + i4));
        __builtin_nontemporal_store(qv, reinterpret_cast<f32x4*>(o_q + i4));
        __builtin_nontemporal_store(qv, reinterpret_cast<f32x4*>(o_zh + i4));
        __builtin_nontemporal_store(iv, reinterpret_cast<f32x4*>(o_idx + i4));
    }
    if (c1 < nchunks) {
        const int i4 = c1 << 2;
        f32x4 qv, iv;
#pragma unroll
        for (int e = 0; e < 4; ++e) { float q, f; argmin16(xb[e], v, q, f); qv[e] = q; iv[e] = f; }
        __builtin_nontemporal_store(xb, reinterpret_cast<f32x4*>(out + i4));
        __builtin_nontemporal_store(qv, reinterpret_cast<f32x4*>(o_q + i4));
        __builtin_nontemporal_store(qv, reinterpret_cast<f32x4*>(o_zh + i4));
        __builtin_nontemporal_store(iv, reinterpret_cast<f32x4*>(o_idx + i4));
    }

    // Generic tail (never executes at N = 2^24 with this grid, kept for safety).
    for (int c = tid + 2 * stride; c < nchunks; c += stride) {
        const int i4 = c << 2;
        const f32x4 xv = *reinterpret_cast<const f32x4*>(x + i4);
        f32x4 qv, iv;
#pragma unroll
        for (int e = 0; e < 4; ++e) { float q, f; argmin16(xv[e], v, q, f); qv[e] = q; iv[e] = f; }
        __builtin_nontemporal_store(xv, reinterpret_cast<f32x4*>(out + i4));
        __builtin_nontemporal_store(qv, reinterpret_cast<f32x4*>(o_q + i4));
        __builtin_nontemporal_store(qv, reinterpret_cast<f32x4*>(o_zh + i4));
        __builtin_nontemporal_store(iv, reinterpret_cast<f32x4*>(o_idx + i4));
    }
}

extern "C" void kernel_launch(void* const* d_in, const int* in_sizes, int n_in,
                              void* d_out, int out_size, void* d_ws, size_t ws_size,
                              hipStream_t stream) {
    const float* x      = (const float*)d_in[0];
    const float* values = (const float*)d_in[1];
    float* out          = (float*)d_out;
    const int n = in_sizes[0];  // 16,777,216

    // 8192 blocks = 32/CU queued; 2M threads -> exactly 2 float4 chunks each.
    const int grid = 8192;

    GlobalQuantizedLatent_87900800680047_kernel<<<grid, BLOCK, 0, stream>>>(
        x, values, out, n);
}